// Round 7
// baseline (388.478 us; speedup 1.0000x reference)
//
#include <hip/hip_runtime.h>
#include <stdint.h>

// ---------------- constants ----------------
constexpr int Bq = 8, Nn = 1025, Dd = 768, Hh = 12, HDd = 64, Pp = 1024;
constexpr int NP = 1088;              // padded N = 17*64
constexpr int MROWS = Bq * Nn;        // 8200
constexpr float EPSI = 1e-6f;

typedef __attribute__((ext_vector_type(8))) short bfrag;   // 8 bf16 = 4 VGPR
typedef __attribute__((ext_vector_type(4))) float ffrag;   // 4 f32
typedef __attribute__((ext_vector_type(4))) float f4;
typedef __attribute__((ext_vector_type(4))) unsigned short us4;

#define MFMA16(a, b, c) __builtin_amdgcn_mfma_f32_16x16x32_bf16((a), (b), (c), 0, 0, 0)

#if __has_builtin(__builtin_amdgcn_exp2f)
#define EXP2(x) __builtin_amdgcn_exp2f(x)
#else
#define EXP2(x) exp2f(x)
#endif

__device__ __forceinline__ unsigned short f2bf(float f) {
  union { float f; uint32_t u; } v{f};
  uint32_t u = v.u;
  return (unsigned short)((u + 0x7fffu + ((u >> 16) & 1u)) >> 16);  // RNE
}
__device__ __forceinline__ float bf2f(unsigned short s) {
  union { uint32_t u; float f; } v; v.u = ((uint32_t)s) << 16; return v.f;
}
// pack 2 f32 -> 2 bf16 in one u32 (lo = a, hi = b), RNE
__device__ __forceinline__ uint32_t pkbf(float a, float b) {
  uint32_t r;
  asm("v_cvt_pk_bf16_f32 %0, %1, %2" : "=v"(r) : "v"(a), "v"(b));
  return r;
}

// async global -> LDS, 16B per lane. LDS dest must be wave-uniform base + lane*16.
__device__ __forceinline__ void gload16(const void* g, void* l) {
  __builtin_amdgcn_global_load_lds((const __attribute__((address_space(1))) unsigned int*)g,
                                   (__attribute__((address_space(3))) unsigned int*)l, 16, 0, 0);
}

// ---------------- fp32 -> bf16 conversion ----------------
__global__ __launch_bounds__(256) void conv_kernel(const float* __restrict__ src,
                                                   unsigned short* __restrict__ dst, int n4) {
  int idx = blockIdx.x * blockDim.x + threadIdx.x;
  int stride = gridDim.x * blockDim.x;
  for (int i = idx; i < n4; i += stride) {
    f4 v = ((const f4*)src)[i];
    us4 o; o[0] = f2bf(v[0]); o[1] = f2bf(v[1]); o[2] = f2bf(v[2]); o[3] = f2bf(v[3]);
    ((us4*)dst)[i] = o;
  }
}

// ---------------- pw = t / (sum(t)+eps) ----------------
__global__ __launch_bounds__(256) void pw_kernel(const float* __restrict__ tr, float* __restrict__ pw) {
  int b = blockIdx.x;
  __shared__ float red[256];
  float s = 0.f;
  for (int j = threadIdx.x; j < Pp; j += 256) s += tr[b * Pp + j];
  red[threadIdx.x] = s; __syncthreads();
  for (int o = 128; o > 0; o >>= 1) { if (threadIdx.x < o) red[threadIdx.x] += red[threadIdx.x + o]; __syncthreads(); }
  float inv = 1.f / (red[0] + EPSI);
  for (int j = threadIdx.x; j < Pp; j += 256) pw[b * Pp + j] = tr[b * Pp + j] * inv;
}

// ---------------- mask bf16 [B][NP][NP], zero padded ----------------
__global__ __launch_bounds__(256) void mask_kernel(const float* __restrict__ graph,
                                                   const float* __restrict__ pw,
                                                   unsigned short* __restrict__ mask) {
  int i = blockIdx.x, b = blockIdx.y;
  unsigned short* mrow = mask + ((size_t)b * NP + i) * NP;
  if (i >= Nn) { for (int j = threadIdx.x; j < NP; j += 256) mrow[j] = 0; return; }
  if (i == 0) {
    for (int j = threadIdx.x; j < NP; j += 256) {
      float v = (j == 0) ? 1.f : (j <= Pp ? pw[b * Pp + j - 1] : 0.f);
      mrow[j] = f2bf(v);
    }
  } else {
    const float* grow = graph + ((size_t)b * Pp + (i - 1)) * Pp;
    for (int j = threadIdx.x; j < NP; j += 256) {
      float v = (j == 0) ? pw[b * Pp + i - 1] : (j <= Pp ? grow[j - 1] : 0.f);
      mrow[j] = f2bf(v);
    }
  }
}

// ---------------- zero pad rows of Q/K and pad cols of VT ----------------
__global__ __launch_bounds__(256) void padzero_kernel(unsigned short* __restrict__ Qo,
                                                      unsigned short* __restrict__ Ko,
                                                      unsigned short* __restrict__ Vo) {
  int bh = blockIdx.x;  // 0..95
  unsigned short* qp = Qo + ((size_t)bh * NP + Nn) * 64;
  unsigned short* kp = Ko + ((size_t)bh * NP + Nn) * 64;
  for (int idx = threadIdx.x; idx < (NP - Nn) * 64; idx += 256) { qp[idx] = 0; kp[idx] = 0; }
  unsigned short* vp = Vo + (size_t)bh * 64 * NP;
  for (int idx = threadIdx.x; idx < 64 * (NP - Nn); idx += 256) {
    int d = idx / (NP - Nn), j = Nn + (idx - d * (NP - Nn));
    vp[(size_t)d * NP + j] = 0;
  }
}

// ---------------- GEMM core: 128x128 tile, BK=64, K=768, bf16 MFMA ----------------
// 2-phase double-buffered pipeline: stage tile t+1 into alternate LDS buffer
// via global_load_lds BEFORE computing tile t; one vmcnt(0) + raw s_barrier per K-step.
__device__ __forceinline__ void gemm_main(const unsigned short* __restrict__ A, int rowA0, int rowAmax,
                                          const unsigned short* __restrict__ Bw, int rowB0,
                                          uint4* lds, ffrag acc[4][4], int tid) {
  const int l = tid & 63, lm = l & 15, lg = l >> 4, w = tid >> 6, wr = w >> 1, wc = w & 1;
  const unsigned short* aS[4]; const unsigned short* bS[4];
#pragma unroll
  for (int q = 0; q < 4; q++) {
    int c = tid + 256 * q, r = c >> 3, p = c & 7, g = p ^ (r & 7);
    int ra = rowA0 + r; if (ra > rowAmax) ra = rowAmax;
    aS[q] = A + (size_t)ra * 768 + 8 * g;
    bS[q] = Bw + (size_t)(rowB0 + r) * 768 + 8 * g;
  }
  uint4* buf0 = lds;
  uint4* buf1 = lds + 2048;
  // prologue: stage tile 0 into buf0
#pragma unroll
  for (int q = 0; q < 4; q++) {
    gload16(aS[q], buf0 + tid + 256 * q);
    gload16(bS[q], buf0 + 1024 + tid + 256 * q);
    aS[q] += 64; bS[q] += 64;
  }
  asm volatile("s_waitcnt vmcnt(0)" ::: "memory");
  __builtin_amdgcn_sched_barrier(0);
  __builtin_amdgcn_s_barrier();
#pragma unroll 1
  for (int kt = 0; kt < 12; kt++) {
    uint4* cur = (kt & 1) ? buf1 : buf0;
    uint4* nxt = (kt & 1) ? buf0 : buf1;
    if (kt < 11) {
#pragma unroll
      for (int q = 0; q < 4; q++) {
        gload16(aS[q], nxt + tid + 256 * q);
        gload16(bS[q], nxt + 1024 + tid + 256 * q);
        aS[q] += 64; bS[q] += 64;
      }
    }
    const bfrag* LA = (const bfrag*)cur;
    const bfrag* LB = (const bfrag*)(cur + 1024);
    bfrag af[4][2], bf_[4][2];
#pragma unroll
    for (int am = 0; am < 4; am++) {
      int row = wr * 64 + am * 16 + lm;
      af[am][0] = LA[row * 8 + ((0 + lg) ^ (row & 7))];
      af[am][1] = LA[row * 8 + ((4 + lg) ^ (row & 7))];
    }
#pragma unroll
    for (int an = 0; an < 4; an++) {
      int row = wc * 64 + an * 16 + lm;
      bf_[an][0] = LB[row * 8 + ((0 + lg) ^ (row & 7))];
      bf_[an][1] = LB[row * 8 + ((4 + lg) ^ (row & 7))];
    }
#pragma unroll
    for (int am = 0; am < 4; am++)
#pragma unroll
      for (int an = 0; an < 4; an++) {
        acc[am][an] = MFMA16(af[am][0], bf_[an][0], acc[am][an]);
        acc[am][an] = MFMA16(af[am][1], bf_[an][1], acc[am][an]);
      }
    asm volatile("s_waitcnt vmcnt(0)" ::: "memory");
    __builtin_amdgcn_sched_barrier(0);
    __builtin_amdgcn_s_barrier();
  }
}

// bijective XCD-chunked mapping (m204)
__device__ __forceinline__ int xcd_chunk_map(int orig, int nwg) {
  int qq = nwg >> 3, rr = nwg & 7;
  int xcd = orig & 7, idx = orig >> 3;
  int base = (xcd < rr) ? xcd * (qq + 1) : rr * (qq + 1) + (xcd - rr) * qq;
  return base + idx;
}

// ---------------- kernel 1: QKV GEMM + scatter epilogue ----------------
__global__ __launch_bounds__(256) void qkv_gemm_kernel(const unsigned short* __restrict__ X,
                                                       const unsigned short* __restrict__ W,
                                                       const float* __restrict__ bias,
                                                       unsigned short* __restrict__ Qo,
                                                       unsigned short* __restrict__ Ko,
                                                       unsigned short* __restrict__ Vo) {
  __shared__ uint4 lds[4096];
  int tid = threadIdx.x;
  int wg = xcd_chunk_map(blockIdx.x, 65 * 18);
  int xt = wg / 18, yt = wg - 18 * xt;
  ffrag zero4 = {0.f, 0.f, 0.f, 0.f};
  ffrag acc[4][4];
#pragma unroll
  for (int i = 0; i < 4; i++)
#pragma unroll
    for (int j = 0; j < 4; j++) acc[i][j] = zero4;
  gemm_main(X, xt * 128, MROWS - 1, W, yt * 128, lds, acc, tid);
  const int l = tid & 63, lm = l & 15, lg = l >> 4, w = tid >> 6, wr = w >> 1, wc = w & 1;
#pragma unroll
  for (int an = 0; an < 4; an++) {
    int gc = yt * 128 + wc * 64 + an * 16 + lm;
    int which = gc / 768, rr = gc - which * 768, h = rr >> 6, hd = rr & 63;
    float bv = bias[gc];
#pragma unroll
    for (int am = 0; am < 4; am++) {
      int grb = xt * 128 + wr * 64 + am * 16 + 4 * lg;
#pragma unroll
      for (int r = 0; r < 4; r++) {
        int gr = grb + r;
        if (gr >= MROWS) continue;
        int b = gr / Nn, i = gr - b * Nn;
        size_t bh = (size_t)(b * Hh + h);
        float v = acc[am][an][r] + bv;
        // Q prescale folds softmax scale AND log2(e): 0.125 * 1.44269504
        if (which == 0)      Qo[(bh * NP + i) * 64 + hd] = f2bf(v * 0.18033688f);
        else if (which == 1) Ko[(bh * NP + i) * 64 + hd] = f2bf(v);
        else                 Vo[(bh * 64 + hd) * NP + i] = f2bf(v);           // V transposed
      }
    }
  }
}

// ---------------- kernel 3: proj GEMM + bias -> fp32 out ----------------
__global__ __launch_bounds__(256) void proj_gemm_kernel(const unsigned short* __restrict__ A,
                                                        const unsigned short* __restrict__ W,
                                                        const float* __restrict__ bias,
                                                        float* __restrict__ out) {
  __shared__ uint4 lds[4096];
  int tid = threadIdx.x;
  int wg = xcd_chunk_map(blockIdx.x, 65 * 6);
  int xt = wg / 6, yt = wg - 6 * xt;
  ffrag zero4 = {0.f, 0.f, 0.f, 0.f};
  ffrag acc[4][4];
#pragma unroll
  for (int i = 0; i < 4; i++)
#pragma unroll
    for (int j = 0; j < 4; j++) acc[i][j] = zero4;
  gemm_main(A, xt * 128, MROWS - 1, W, yt * 128, lds, acc, tid);
  const int l = tid & 63, lm = l & 15, lg = l >> 4, w = tid >> 6, wr = w >> 1, wc = w & 1;
#pragma unroll
  for (int an = 0; an < 4; an++) {
    int gc = yt * 128 + wc * 64 + an * 16 + lm;
    float bv = bias[gc];
#pragma unroll
    for (int am = 0; am < 4; am++) {
      int grb = xt * 128 + wr * 64 + am * 16 + 4 * lg;
#pragma unroll
      for (int r = 0; r < 4; r++) {
        int gr = grb + r;
        if (gr >= MROWS) continue;
        out[(size_t)gr * 768 + gc] = acc[am][an][r] + bv;
      }
    }
  }
}

// ---------------- kernel 2: fused masked attention, direct-global K/V, barrier-free ----------------
// K/V per head (278KB) is L2-resident (17 q-blocks per head reuse it; XCD-pinned by swizzle).
// Operand fragments are read straight from global into MFMA registers — no K/V LDS,
// no __syncthreads: each wave is fully independent; TLP (VGPR-bound ~5 blocks/CU) hides L2 latency.
// Only LDS use: per-wave P tile (2KB) for the P^T->P redistribution between QK^T and PV.
__global__ __launch_bounds__(256) void attn_kernel(const unsigned short* __restrict__ Qg,
                                                   const unsigned short* __restrict__ Kg,
                                                   const unsigned short* __restrict__ Vg,
                                                   const unsigned short* __restrict__ Mg,
                                                   unsigned short* __restrict__ Og) {
  __shared__ uint4 smem[512];  // 4 waves x 2KB P tile
  int tid = threadIdx.x, w = tid >> 6, l = tid & 63, lm = l & 15, lg = l >> 4;
  int bx = blockIdx.x;
  int b = bx & 7, t5 = bx >> 3;
  int h = t5 % 12, ib = t5 / 12;
  size_t bh = (size_t)(b * Hh + h);
  const unsigned short* Qb = Qg + bh * NP * 64;
  const unsigned short* Kb = Kg + bh * NP * 64;
  const unsigned short* Vb = Vg + bh * 64 * NP;
  int i0 = ib * 64 + w * 16;
  int irow = i0 + lm;
  const unsigned short* Mrow = Mg + (size_t)b * NP * NP + (size_t)irow * NP;

  bfrag qf0 = *(const bfrag*)(Qb + (size_t)irow * 64 + 8 * lg);
  bfrag qf1 = *(const bfrag*)(Qb + (size_t)irow * 64 + 32 + 8 * lg);

  ffrag zero4 = {0.f, 0.f, 0.f, 0.f};
  ffrag oacc[4] = {zero4, zero4, zero4, zero4};
  float Tp = 0.f;

  char* Pbase = (char*)smem + w * 2048;   // per-wave P tile [16 i][64 j] bf16, chunk-XOR

  // per-lane K row base (row = jm*16+lm within tile) and V row base (row = dm*16+lm)
  const unsigned short* Krow = Kb + (size_t)lm * 64 + 8 * lg;       // + (t*64+jm*16)*64
  const unsigned short* Vrow = Vb + (size_t)lm * NP;                // + dm*16*NP + j

#pragma unroll 1
  for (int t = 0; t < 17; t++) {
    int j0 = t * 64;
    // mask for this tile: 4x 8B vector loads
    us4 mva[4];
#pragma unroll
    for (int jm = 0; jm < 4; jm++) mva[jm] = *(const us4*)(Mrow + j0 + 16 * jm + 4 * lg);

    // --- QK^T (swapped): A = K rows direct from global (L2), B = Q regs ---
    ffrag s[4];
    __builtin_amdgcn_s_setprio(1);
#pragma unroll
    for (int jm = 0; jm < 4; jm++) {
      const unsigned short* kp = Krow + (size_t)(j0 + jm * 16) * 64;
      bfrag a0 = *(const bfrag*)(kp);
      bfrag a1 = *(const bfrag*)(kp + 32);
      ffrag a = zero4;
      a = MFMA16(a0, qf0, a);
      a = MFMA16(a1, qf1, a);
      s[jm] = a;
    }
    __builtin_amdgcn_s_setprio(0);
    // --- p = exp2(s); pm = p*mask; accumulate T; pack + write P ---
#pragma unroll
    for (int jm = 0; jm < 4; jm++) {
      float p0 = EXP2(s[jm][0]), p1 = EXP2(s[jm][1]), p2 = EXP2(s[jm][2]), p3 = EXP2(s[jm][3]);
      float q0 = p0 * bf2f(mva[jm][0]), q1 = p1 * bf2f(mva[jm][1]);
      float q2 = p2 * bf2f(mva[jm][2]), q3 = p3 * bf2f(mva[jm][3]);
      Tp += (q0 + q1) + (q2 + q3);
      uint2 pk; pk.x = pkbf(q0, q1); pk.y = pkbf(q2, q3);
      int cpos = (((jm << 1) | (lg >> 1)) ^ (lm & 7));
      *(uint2*)(Pbase + lm * 128 + cpos * 16 + 8 * (lg & 1)) = pk;
    }
    // --- PV: A = P from LDS (chunk-XOR read), B = V^T rows direct from global (L2) ---
    __builtin_amdgcn_s_setprio(1);
#pragma unroll
    for (int ks = 0; ks < 2; ks++) {
      bfrag pa = *(const bfrag*)(Pbase + lm * 128 + ((((ks << 2) | lg)) ^ (lm & 7)) * 16);
#pragma unroll
      for (int dm = 0; dm < 4; dm++) {
        bfrag vb = *(const bfrag*)(Vrow + (size_t)dm * 16 * NP + j0 + 8 * (ks * 4 + lg));
        oacc[dm] = MFMA16(pa, vb, oacc[dm]);
      }
    }
    __builtin_amdgcn_s_setprio(0);
  }
  // --- finalize: reduce T across lg lanes; broadcast per-row denominators ---
  Tp += __shfl_xor(Tp, 16); Tp += __shfl_xor(Tp, 32);
  float dn_row = 1.f / Tp;   // eps*Z term dropped (rel err ~2e-6)
  float dn[4];
#pragma unroll
  for (int r = 0; r < 4; r++) dn[r] = __shfl(dn_row, 4 * lg + r);
#pragma unroll
  for (int dm = 0; dm < 4; dm++)
#pragma unroll
    for (int r = 0; r < 4; r++) {
      int i = i0 + 4 * lg + r;
      if (i < Nn) Og[((size_t)(b * Nn + i)) * Dd + h * 64 + dm * 16 + lm] = f2bf(oacc[dm][r] * dn[r]);
    }
}

// ---------------- launch ----------------
extern "C" void kernel_launch(void* const* d_in, const int* in_sizes, int n_in,
                              void* d_out, int out_size, void* d_ws, size_t ws_size,
                              hipStream_t stream) {
  const float* x      = (const float*)d_in[0];
  const float* graph  = (const float*)d_in[1];
  const float* transf = (const float*)d_in[2];
  const float* Wqkv   = (const float*)d_in[3];
  const float* bqkv   = (const float*)d_in[4];
  const float* Wproj  = (const float*)d_in[5];
  const float* bproj  = (const float*)d_in[6];
  float* out = (float*)d_out;
  char* ws = (char*)d_ws;

  unsigned short* xbf  = (unsigned short*)(ws + 0);                 // 12,595,200 (also attn_out)
  unsigned short* wqb  = (unsigned short*)(ws + 12595200);          //  3,538,944
  unsigned short* wpb  = (unsigned short*)(ws + 16134144);          //  1,179,648
  unsigned short* Qb   = (unsigned short*)(ws + 17313792);          // 13,369,344
  unsigned short* Kb   = (unsigned short*)(ws + 30683136);          // 13,369,344
  unsigned short* Vb   = (unsigned short*)(ws + 44052480);          // 13,369,344
  float*          pw   = (float*)(ws + 57421824);                   //     32,768
  unsigned short* mask = (unsigned short*)(ws + 57454592);          // 18,939,904
  unsigned short* aob  = xbf;  // attention output bf16 [8200][768]

  conv_kernel<<<2048, 256, 0, stream>>>(x, xbf, (MROWS * Dd) / 4);
  conv_kernel<<<1728, 256, 0, stream>>>(Wqkv, wqb, (3 * Dd * Dd) / 4);
  conv_kernel<<<576, 256, 0, stream>>>(Wproj, wpb, (Dd * Dd) / 4);
  pw_kernel<<<Bq, 256, 0, stream>>>(transf, pw);
  mask_kernel<<<dim3(NP, Bq), 256, 0, stream>>>(graph, pw, mask);
  padzero_kernel<<<96, 256, 0, stream>>>(Qb, Kb, Vb);
  qkv_gemm_kernel<<<65 * 18, 256, 0, stream>>>(xbf, wqb, bqkv, Qb, Kb, Vb);
  attn_kernel<<<1632, 256, 0, stream>>>(Qb, Kb, Vb, mask, aob);
  proj_gemm_kernel<<<65 * 6, 256, 0, stream>>>(aob, wpb, bproj, out);
}

// Round 8
// 209.473 us; speedup vs baseline: 1.8545x; 1.8545x over previous
//
#include <hip/hip_runtime.h>
#include <stdint.h>

// ---------------- constants ----------------
constexpr int Bq = 8, Nn = 1025, Dd = 768, Hh = 12, HDd = 64, Pp = 1024;
constexpr int NP = 1088;              // padded N = 17*64
constexpr int MROWS = Bq * Nn;        // 8200
constexpr float EPSI = 1e-6f;

typedef __attribute__((ext_vector_type(8))) short bfrag;   // 8 bf16 = 4 VGPR
typedef __attribute__((ext_vector_type(4))) float ffrag;   // 4 f32
typedef __attribute__((ext_vector_type(4))) float f4;
typedef __attribute__((ext_vector_type(4))) unsigned short us4;

#define MFMA16(a, b, c) __builtin_amdgcn_mfma_f32_16x16x32_bf16((a), (b), (c), 0, 0, 0)

#if __has_builtin(__builtin_amdgcn_exp2f)
#define EXP2(x) __builtin_amdgcn_exp2f(x)
#else
#define EXP2(x) exp2f(x)
#endif

__device__ __forceinline__ unsigned short f2bf(float f) {
  union { float f; uint32_t u; } v{f};
  uint32_t u = v.u;
  return (unsigned short)((u + 0x7fffu + ((u >> 16) & 1u)) >> 16);  // RNE
}
__device__ __forceinline__ float bf2f(unsigned short s) {
  union { uint32_t u; float f; } v; v.u = ((uint32_t)s) << 16; return v.f;
}
// pack 2 f32 -> 2 bf16 in one u32 (lo = a, hi = b), RNE
__device__ __forceinline__ uint32_t pkbf(float a, float b) {
  uint32_t r;
  asm("v_cvt_pk_bf16_f32 %0, %1, %2" : "=v"(r) : "v"(a), "v"(b));
  return r;
}

// async global -> LDS, 16B per lane. LDS dest must be wave-uniform base + lane*16.
__device__ __forceinline__ void gload16(const void* g, void* l) {
  __builtin_amdgcn_global_load_lds((const __attribute__((address_space(1))) unsigned int*)g,
                                   (__attribute__((address_space(3))) unsigned int*)l, 16, 0, 0);
}

// ---------------- fp32 -> bf16 conversion ----------------
__global__ __launch_bounds__(256) void conv_kernel(const float* __restrict__ src,
                                                   unsigned short* __restrict__ dst, int n4) {
  int idx = blockIdx.x * blockDim.x + threadIdx.x;
  int stride = gridDim.x * blockDim.x;
  for (int i = idx; i < n4; i += stride) {
    f4 v = ((const f4*)src)[i];
    us4 o; o[0] = f2bf(v[0]); o[1] = f2bf(v[1]); o[2] = f2bf(v[2]); o[3] = f2bf(v[3]);
    ((us4*)dst)[i] = o;
  }
}

// ---------------- pw = t / (sum(t)+eps) ----------------
__global__ __launch_bounds__(256) void pw_kernel(const float* __restrict__ tr, float* __restrict__ pw) {
  int b = blockIdx.x;
  __shared__ float red[256];
  float s = 0.f;
  for (int j = threadIdx.x; j < Pp; j += 256) s += tr[b * Pp + j];
  red[threadIdx.x] = s; __syncthreads();
  for (int o = 128; o > 0; o >>= 1) { if (threadIdx.x < o) red[threadIdx.x] += red[threadIdx.x + o]; __syncthreads(); }
  float inv = 1.f / (red[0] + EPSI);
  for (int j = threadIdx.x; j < Pp; j += 256) pw[b * Pp + j] = tr[b * Pp + j] * inv;
}

// ---------------- mask bf16 [B][NP][NP], zero padded ----------------
__global__ __launch_bounds__(256) void mask_kernel(const float* __restrict__ graph,
                                                   const float* __restrict__ pw,
                                                   unsigned short* __restrict__ mask) {
  int i = blockIdx.x, b = blockIdx.y;
  unsigned short* mrow = mask + ((size_t)b * NP + i) * NP;
  if (i >= Nn) { for (int j = threadIdx.x; j < NP; j += 256) mrow[j] = 0; return; }
  if (i == 0) {
    for (int j = threadIdx.x; j < NP; j += 256) {
      float v = (j == 0) ? 1.f : (j <= Pp ? pw[b * Pp + j - 1] : 0.f);
      mrow[j] = f2bf(v);
    }
  } else {
    const float* grow = graph + ((size_t)b * Pp + (i - 1)) * Pp;
    for (int j = threadIdx.x; j < NP; j += 256) {
      float v = (j == 0) ? pw[b * Pp + i - 1] : (j <= Pp ? grow[j - 1] : 0.f);
      mrow[j] = f2bf(v);
    }
  }
}

// ---------------- zero pad rows of Q/K and pad cols of VT ----------------
__global__ __launch_bounds__(256) void padzero_kernel(unsigned short* __restrict__ Qo,
                                                      unsigned short* __restrict__ Ko,
                                                      unsigned short* __restrict__ Vo) {
  int bh = blockIdx.x;  // 0..95
  unsigned short* qp = Qo + ((size_t)bh * NP + Nn) * 64;
  unsigned short* kp = Ko + ((size_t)bh * NP + Nn) * 64;
  for (int idx = threadIdx.x; idx < (NP - Nn) * 64; idx += 256) { qp[idx] = 0; kp[idx] = 0; }
  unsigned short* vp = Vo + (size_t)bh * 64 * NP;
  for (int idx = threadIdx.x; idx < 64 * (NP - Nn); idx += 256) {
    int d = idx / (NP - Nn), j = Nn + (idx - d * (NP - Nn));
    vp[(size_t)d * NP + j] = 0;
  }
}

// ---------------- GEMM core: 128x128 tile, BK=64, K=768, bf16 MFMA ----------------
// 2-phase double-buffered pipeline: stage tile t+1 into alternate LDS buffer
// via global_load_lds BEFORE computing tile t; one vmcnt(0) + raw s_barrier per K-step.
__device__ __forceinline__ void gemm_main(const unsigned short* __restrict__ A, int rowA0, int rowAmax,
                                          const unsigned short* __restrict__ Bw, int rowB0,
                                          uint4* lds, ffrag acc[4][4], int tid) {
  const int l = tid & 63, lm = l & 15, lg = l >> 4, w = tid >> 6, wr = w >> 1, wc = w & 1;
  const unsigned short* aS[4]; const unsigned short* bS[4];
#pragma unroll
  for (int q = 0; q < 4; q++) {
    int c = tid + 256 * q, r = c >> 3, p = c & 7, g = p ^ (r & 7);
    int ra = rowA0 + r; if (ra > rowAmax) ra = rowAmax;
    aS[q] = A + (size_t)ra * 768 + 8 * g;
    bS[q] = Bw + (size_t)(rowB0 + r) * 768 + 8 * g;
  }
  uint4* buf0 = lds;
  uint4* buf1 = lds + 2048;
  // prologue: stage tile 0 into buf0
#pragma unroll
  for (int q = 0; q < 4; q++) {
    gload16(aS[q], buf0 + tid + 256 * q);
    gload16(bS[q], buf0 + 1024 + tid + 256 * q);
    aS[q] += 64; bS[q] += 64;
  }
  asm volatile("s_waitcnt vmcnt(0)" ::: "memory");
  __builtin_amdgcn_sched_barrier(0);
  __builtin_amdgcn_s_barrier();
#pragma unroll 1
  for (int kt = 0; kt < 12; kt++) {
    uint4* cur = (kt & 1) ? buf1 : buf0;
    uint4* nxt = (kt & 1) ? buf0 : buf1;
    if (kt < 11) {
#pragma unroll
      for (int q = 0; q < 4; q++) {
        gload16(aS[q], nxt + tid + 256 * q);
        gload16(bS[q], nxt + 1024 + tid + 256 * q);
        aS[q] += 64; bS[q] += 64;
      }
    }
    const bfrag* LA = (const bfrag*)cur;
    const bfrag* LB = (const bfrag*)(cur + 1024);
    bfrag af[4][2], bf_[4][2];
#pragma unroll
    for (int am = 0; am < 4; am++) {
      int row = wr * 64 + am * 16 + lm;
      af[am][0] = LA[row * 8 + ((0 + lg) ^ (row & 7))];
      af[am][1] = LA[row * 8 + ((4 + lg) ^ (row & 7))];
    }
#pragma unroll
    for (int an = 0; an < 4; an++) {
      int row = wc * 64 + an * 16 + lm;
      bf_[an][0] = LB[row * 8 + ((0 + lg) ^ (row & 7))];
      bf_[an][1] = LB[row * 8 + ((4 + lg) ^ (row & 7))];
    }
#pragma unroll
    for (int am = 0; am < 4; am++)
#pragma unroll
      for (int an = 0; an < 4; an++) {
        acc[am][an] = MFMA16(af[am][0], bf_[an][0], acc[am][an]);
        acc[am][an] = MFMA16(af[am][1], bf_[an][1], acc[am][an]);
      }
    asm volatile("s_waitcnt vmcnt(0)" ::: "memory");
    __builtin_amdgcn_sched_barrier(0);
    __builtin_amdgcn_s_barrier();
  }
}

// bijective XCD-chunked mapping (m204)
__device__ __forceinline__ int xcd_chunk_map(int orig, int nwg) {
  int qq = nwg >> 3, rr = nwg & 7;
  int xcd = orig & 7, idx = orig >> 3;
  int base = (xcd < rr) ? xcd * (qq + 1) : rr * (qq + 1) + (xcd - rr) * qq;
  return base + idx;
}

// ---------------- kernel 1: QKV GEMM + scatter epilogue ----------------
__global__ __launch_bounds__(256) void qkv_gemm_kernel(const unsigned short* __restrict__ X,
                                                       const unsigned short* __restrict__ W,
                                                       const float* __restrict__ bias,
                                                       unsigned short* __restrict__ Qo,
                                                       unsigned short* __restrict__ Ko,
                                                       unsigned short* __restrict__ Vo) {
  __shared__ uint4 lds[4096];
  int tid = threadIdx.x;
  int wg = xcd_chunk_map(blockIdx.x, 65 * 18);
  int xt = wg / 18, yt = wg - 18 * xt;
  ffrag zero4 = {0.f, 0.f, 0.f, 0.f};
  ffrag acc[4][4];
#pragma unroll
  for (int i = 0; i < 4; i++)
#pragma unroll
    for (int j = 0; j < 4; j++) acc[i][j] = zero4;
  gemm_main(X, xt * 128, MROWS - 1, W, yt * 128, lds, acc, tid);
  const int l = tid & 63, lm = l & 15, lg = l >> 4, w = tid >> 6, wr = w >> 1, wc = w & 1;
#pragma unroll
  for (int an = 0; an < 4; an++) {
    int gc = yt * 128 + wc * 64 + an * 16 + lm;
    int which = gc / 768, rr = gc - which * 768, h = rr >> 6, hd = rr & 63;
    float bv = bias[gc];
#pragma unroll
    for (int am = 0; am < 4; am++) {
      int grb = xt * 128 + wr * 64 + am * 16 + 4 * lg;
#pragma unroll
      for (int r = 0; r < 4; r++) {
        int gr = grb + r;
        if (gr >= MROWS) continue;
        int b = gr / Nn, i = gr - b * Nn;
        size_t bh = (size_t)(b * Hh + h);
        float v = acc[am][an][r] + bv;
        // Q prescale folds softmax scale AND log2(e): 0.125 * 1.44269504
        if (which == 0)      Qo[(bh * NP + i) * 64 + hd] = f2bf(v * 0.18033688f);
        else if (which == 1) Ko[(bh * NP + i) * 64 + hd] = f2bf(v);
        else                 Vo[(bh * 64 + hd) * NP + i] = f2bf(v);           // V transposed
      }
    }
  }
}

// ---------------- kernel 3: proj GEMM + bias -> fp32 out ----------------
__global__ __launch_bounds__(256) void proj_gemm_kernel(const unsigned short* __restrict__ A,
                                                        const unsigned short* __restrict__ W,
                                                        const float* __restrict__ bias,
                                                        float* __restrict__ out) {
  __shared__ uint4 lds[4096];
  int tid = threadIdx.x;
  int wg = xcd_chunk_map(blockIdx.x, 65 * 6);
  int xt = wg / 6, yt = wg - 6 * xt;
  ffrag zero4 = {0.f, 0.f, 0.f, 0.f};
  ffrag acc[4][4];
#pragma unroll
  for (int i = 0; i < 4; i++)
#pragma unroll
    for (int j = 0; j < 4; j++) acc[i][j] = zero4;
  gemm_main(A, xt * 128, MROWS - 1, W, yt * 128, lds, acc, tid);
  const int l = tid & 63, lm = l & 15, lg = l >> 4, w = tid >> 6, wr = w >> 1, wc = w & 1;
#pragma unroll
  for (int an = 0; an < 4; an++) {
    int gc = yt * 128 + wc * 64 + an * 16 + lm;
    float bv = bias[gc];
#pragma unroll
    for (int am = 0; am < 4; am++) {
      int grb = xt * 128 + wr * 64 + am * 16 + 4 * lg;
#pragma unroll
      for (int r = 0; r < 4; r++) {
        int gr = grb + r;
        if (gr >= MROWS) continue;
        out[(size_t)gr * 768 + gc] = acc[am][an][r] + bv;
      }
    }
  }
}

// ---------------- kernel 2: fused masked attention, 2 q-blocks/block ----------------
// R5 structure (dbuf gload_lds K/V staging) + K/V FRAGMENT REUSE: block covers 128
// q-rows (two 64-row sub-blocks a,b); QK^T A-frags (K rows) and PV B-frags (V rows)
// are q-independent -> read once from LDS, used for both sub-blocks. Halves per-q-row
// LDS reads, staging traffic, and barriers. P tile is wave-private, reused a->b.
__global__ __launch_bounds__(256) void attn_kernel(const unsigned short* __restrict__ Qg,
                                                   const unsigned short* __restrict__ Kg,
                                                   const unsigned short* __restrict__ Vg,
                                                   const unsigned short* __restrict__ Mg,
                                                   unsigned short* __restrict__ Og) {
  __shared__ uint4 smem[2560];  // dbuf (K 8KB + V 8KB) x2 | P 4x2KB = 40KB
  int tid = threadIdx.x, w = tid >> 6, l = tid & 63, lm = l & 15, lg = l >> 4;
  int bx = blockIdx.x;
  int b = bx & 7, t5 = bx >> 3;        // grid 864 = 8 * (12*9)
  int h = t5 % 12, ib = t5 / 12;       // ib 0..8, 128 q-rows each
  size_t bh = (size_t)(b * Hh + h);
  const unsigned short* Qb = Qg + bh * NP * 64;
  const unsigned short* Kb = Kg + bh * NP * 64;
  const unsigned short* Vb = Vg + bh * 64 * NP;
  int i0a = ib * 128 + w * 16;
  int i0b = i0a + 64;
  int irowa = i0a + lm; if (irowa > NP - 1) irowa = NP - 1;   // clamped rows are zero-padded
  int irowb = i0b + lm; if (irowb > NP - 1) irowb = NP - 1;
  const unsigned short* Mrowa = Mg + (size_t)b * NP * NP + (size_t)irowa * NP;
  const unsigned short* Mrowb = Mg + (size_t)b * NP * NP + (size_t)irowb * NP;

  bfrag qa0 = *(const bfrag*)(Qb + (size_t)irowa * 64 + 8 * lg);
  bfrag qa1 = *(const bfrag*)(Qb + (size_t)irowa * 64 + 32 + 8 * lg);
  bfrag qb0 = *(const bfrag*)(Qb + (size_t)irowb * 64 + 8 * lg);
  bfrag qb1 = *(const bfrag*)(Qb + (size_t)irowb * 64 + 32 + 8 * lg);

  ffrag zero4 = {0.f, 0.f, 0.f, 0.f};
  ffrag oaccA[4] = {zero4, zero4, zero4, zero4};
  ffrag oaccB[4] = {zero4, zero4, zero4, zero4};
  float TpA = 0.f, TpB = 0.f;

  // staging (pre-swizzled global addr, linear LDS dest): chunk c=tid -> row rS, c=tid+256 -> row rS+32
  int rS = tid >> 3, pS = tid & 7;
  int rS2 = rS + 32;
  const unsigned short* kS0 = Kb + (size_t)rS * 64 + 8 * (pS ^ (rS & 7));
  const unsigned short* kS1 = Kb + (size_t)rS2 * 64 + 8 * (pS ^ (rS2 & 7));
  const unsigned short* vS0 = Vb + (size_t)rS * NP + 8 * (pS ^ (rS & 7));
  const unsigned short* vS1 = Vb + (size_t)rS2 * NP + 8 * (pS ^ (rS2 & 7));

  char* Pbase = (char*)(smem + 2048) + w * 2048;   // per-wave P tile [16 i][64 j] bf16, chunk-XOR

  // prologue: stage tile 0 into buffer 0
  gload16(kS0, smem + tid);
  gload16(kS1, smem + tid + 256);
  gload16(vS0, smem + 512 + tid);
  gload16(vS1, smem + 512 + tid + 256);
  asm volatile("s_waitcnt vmcnt(0)" ::: "memory");
  __builtin_amdgcn_sched_barrier(0);
  __builtin_amdgcn_s_barrier();

#pragma unroll 1
  for (int t = 0; t < 17; t++) {
    int cb = (t & 1) << 10;   // current buffer: 1024 uint4 each (K 512 | V 512)
    if (t < 16) {
      int nb = ((t + 1) & 1) << 10;
      size_t ko = (size_t)(t + 1) * 4096;   // K advances 64 rows * 64 elems
      int vo = (t + 1) * 64;                // V^T advances 64 columns
      gload16(kS0 + ko, smem + nb + tid);
      gload16(kS1 + ko, smem + nb + tid + 256);
      gload16(vS0 + vo, smem + nb + 512 + tid);
      gload16(vS1 + vo, smem + nb + 512 + tid + 256);
    }
    int j0 = t * 64;
    us4 mvA[4], mvB[4];
#pragma unroll
    for (int jm = 0; jm < 4; jm++) {
      mvA[jm] = *(const us4*)(Mrowa + j0 + 16 * jm + 4 * lg);
      mvB[jm] = *(const us4*)(Mrowb + j0 + 16 * jm + 4 * lg);
    }
    const bfrag* LK = (const bfrag*)(smem + cb);
    const bfrag* LV = (const bfrag*)(smem + cb + 512);

    // --- K fragments: read ONCE, used by both sub-blocks ---
    bfrag ka[4], kb2[4];
#pragma unroll
    for (int jm = 0; jm < 4; jm++) {
      int row = jm * 16 + lm;
      ka[jm]  = LK[row * 8 + ((0 + lg) ^ (row & 7))];
      kb2[jm] = LK[row * 8 + ((4 + lg) ^ (row & 7))];
    }
    // --- QK^T both sub-blocks ---
    ffrag sa[4], sb[4];
    __builtin_amdgcn_s_setprio(1);
#pragma unroll
    for (int jm = 0; jm < 4; jm++) {
      ffrag a = zero4;
      a = MFMA16(ka[jm], qa0, a);
      a = MFMA16(kb2[jm], qa1, a);
      sa[jm] = a;
      ffrag bb = zero4;
      bb = MFMA16(ka[jm], qb0, bb);
      bb = MFMA16(kb2[jm], qb1, bb);
      sb[jm] = bb;
    }
    __builtin_amdgcn_s_setprio(0);

    // --- V fragments: read ONCE, used by both sub-blocks ---
    bfrag vf[2][4];
#pragma unroll
    for (int ks = 0; ks < 2; ks++)
#pragma unroll
      for (int dm = 0; dm < 4; dm++) {
        int vrow = dm * 16 + lm;
        vf[ks][dm] = LV[vrow * 8 + ((ks * 4 + lg) ^ (vrow & 7))];
      }

    // --- sub-block a: softmax -> P -> PV ---
#pragma unroll
    for (int jm = 0; jm < 4; jm++) {
      float p0 = EXP2(sa[jm][0]), p1 = EXP2(sa[jm][1]), p2 = EXP2(sa[jm][2]), p3 = EXP2(sa[jm][3]);
      float q0 = p0 * bf2f(mvA[jm][0]), q1 = p1 * bf2f(mvA[jm][1]);
      float q2 = p2 * bf2f(mvA[jm][2]), q3 = p3 * bf2f(mvA[jm][3]);
      TpA += (q0 + q1) + (q2 + q3);
      uint2 pk; pk.x = pkbf(q0, q1); pk.y = pkbf(q2, q3);
      int cpos = (((jm << 1) | (lg >> 1)) ^ (lm & 7));
      *(uint2*)(Pbase + lm * 128 + cpos * 16 + 8 * (lg & 1)) = pk;
    }
    __builtin_amdgcn_s_setprio(1);
#pragma unroll
    for (int ks = 0; ks < 2; ks++) {
      bfrag pa = *(const bfrag*)(Pbase + lm * 128 + ((((ks << 2) | lg)) ^ (lm & 7)) * 16);
#pragma unroll
      for (int dm = 0; dm < 4; dm++) oaccA[dm] = MFMA16(pa, vf[ks][dm], oaccA[dm]);
    }
    __builtin_amdgcn_s_setprio(0);

    // --- sub-block b: softmax -> P (reuse wave-private tile) -> PV ---
#pragma unroll
    for (int jm = 0; jm < 4; jm++) {
      float p0 = EXP2(sb[jm][0]), p1 = EXP2(sb[jm][1]), p2 = EXP2(sb[jm][2]), p3 = EXP2(sb[jm][3]);
      float q0 = p0 * bf2f(mvB[jm][0]), q1 = p1 * bf2f(mvB[jm][1]);
      float q2 = p2 * bf2f(mvB[jm][2]), q3 = p3 * bf2f(mvB[jm][3]);
      TpB += (q0 + q1) + (q2 + q3);
      uint2 pk; pk.x = pkbf(q0, q1); pk.y = pkbf(q2, q3);
      int cpos = (((jm << 1) | (lg >> 1)) ^ (lm & 7));
      *(uint2*)(Pbase + lm * 128 + cpos * 16 + 8 * (lg & 1)) = pk;
    }
    __builtin_amdgcn_s_setprio(1);
#pragma unroll
    for (int ks = 0; ks < 2; ks++) {
      bfrag pa = *(const bfrag*)(Pbase + lm * 128 + ((((ks << 2) | lg)) ^ (lm & 7)) * 16);
#pragma unroll
      for (int dm = 0; dm < 4; dm++) oaccB[dm] = MFMA16(pa, vf[ks][dm], oaccB[dm]);
    }
    __builtin_amdgcn_s_setprio(0);

    // next tile's K/V landed; all waves done reading current buffers.
    asm volatile("s_waitcnt vmcnt(0)" ::: "memory");
    __builtin_amdgcn_sched_barrier(0);
    __builtin_amdgcn_s_barrier();
  }
  // --- finalize: reduce T across lg lanes; per-row denominators; store both sub-blocks ---
  TpA += __shfl_xor(TpA, 16); TpA += __shfl_xor(TpA, 32);
  TpB += __shfl_xor(TpB, 16); TpB += __shfl_xor(TpB, 32);
  float dnA_row = 1.f / TpA;   // eps*Z term dropped (rel err ~2e-6)
  float dnB_row = 1.f / TpB;
  float dnA[4], dnB[4];
#pragma unroll
  for (int r = 0; r < 4; r++) { dnA[r] = __shfl(dnA_row, 4 * lg + r); dnB[r] = __shfl(dnB_row, 4 * lg + r); }
#pragma unroll
  for (int dm = 0; dm < 4; dm++)
#pragma unroll
    for (int r = 0; r < 4; r++) {
      int ia = i0a + 4 * lg + r;
      if (ia < Nn) Og[((size_t)(b * Nn + ia)) * Dd + h * 64 + dm * 16 + lm] = f2bf(oaccA[dm][r] * dnA[r]);
      int ibr = i0b + 4 * lg + r;
      if (ibr < Nn) Og[((size_t)(b * Nn + ibr)) * Dd + h * 64 + dm * 16 + lm] = f2bf(oaccB[dm][r] * dnB[r]);
    }
}

// ---------------- launch ----------------
extern "C" void kernel_launch(void* const* d_in, const int* in_sizes, int n_in,
                              void* d_out, int out_size, void* d_ws, size_t ws_size,
                              hipStream_t stream) {
  const float* x      = (const float*)d_in[0];
  const float* graph  = (const float*)d_in[1];
  const float* transf = (const float*)d_in[2];
  const float* Wqkv   = (const float*)d_in[3];
  const float* bqkv   = (const float*)d_in[4];
  const float* Wproj  = (const float*)d_in[5];
  const float* bproj  = (const float*)d_in[6];
  float* out = (float*)d_out;
  char* ws = (char*)d_ws;

  unsigned short* xbf  = (unsigned short*)(ws + 0);                 // 12,595,200 (also attn_out)
  unsigned short* wqb  = (unsigned short*)(ws + 12595200);          //  3,538,944
  unsigned short* wpb  = (unsigned short*)(ws + 16134144);          //  1,179,648
  unsigned short* Qb   = (unsigned short*)(ws + 17313792);          // 13,369,344
  unsigned short* Kb   = (unsigned short*)(ws + 30683136);          // 13,369,344
  unsigned short* Vb   = (unsigned short*)(ws + 44052480);          // 13,369,344
  float*          pw   = (float*)(ws + 57421824);                   //     32,768
  unsigned short* mask = (unsigned short*)(ws + 57454592);          // 18,939,904
  unsigned short* aob  = xbf;  // attention output bf16 [8200][768]

  conv_kernel<<<2048, 256, 0, stream>>>(x, xbf, (MROWS * Dd) / 4);
  conv_kernel<<<1728, 256, 0, stream>>>(Wqkv, wqb, (3 * Dd * Dd) / 4);
  conv_kernel<<<576, 256, 0, stream>>>(Wproj, wpb, (Dd * Dd) / 4);
  pw_kernel<<<Bq, 256, 0, stream>>>(transf, pw);
  mask_kernel<<<dim3(NP, Bq), 256, 0, stream>>>(graph, pw, mask);
  padzero_kernel<<<96, 256, 0, stream>>>(Qb, Kb, Vb);
  qkv_gemm_kernel<<<65 * 18, 256, 0, stream>>>(xbf, wqb, bqkv, Qb, Kb, Vb);
  attn_kernel<<<864, 256, 0, stream>>>(Qb, Kb, Vb, mask, aob);
  proj_gemm_kernel<<<65 * 6, 256, 0, stream>>>(aob, wpb, bproj, out);
}